// Round 11
// baseline (69.188 us; speedup 1.0000x reference)
//
#include <hip/hip_runtime.h>
#include <hip/hip_bf16.h>

// Problem constants (S4Layer: T=4096, B=16, D=128, S=256)
#define T_  4096
#define B_  16
#define D_  128
#define S_  256
#define WND 32             // chunk length = GEMM t-tile
#define C4  (T_/WND)       // 128 chunks

using bf8   = __attribute__((ext_vector_type(8))) short;   // 8 bf16 (4 VGPRs)
using f32x4 = __attribute__((ext_vector_type(4))) float;   // MFMA acc

__device__ inline float bfbits(unsigned short h) {
    return __builtin_bit_cast(float, (unsigned)h << 16);
}
__device__ inline unsigned short bf16bits(float f) {
    return __hip_bfloat16_raw(__float2bfloat16(f)).x;
}

// ---------------- K1: parameters (hoisted, computed ONCE) -------------------
__global__ __launch_bounds__(256) void k_params(
        const float* __restrict__ lna, const float* __restrict__ bmat,
        const float* __restrict__ ldt,
        float* __restrict__ abar, float* __restrict__ aw32,
        __hip_bfloat16* __restrict__ bbar) {
    if (blockIdx.x < 128) {
        int idx = blockIdx.x * 256 + threadIdx.x;   // (s,d)
        int s = idx >> 7;
        float la = fminf(fmaxf(lna[s], -8.f), 4.f);
        float ar = -expf(la);
        float lt = fminf(fmaxf(ldt[s], -8.f), 1.f);
        float dt = expf(lt);
        float xx = dt * ar;
        float ratio = (fabsf(xx) < 1e-6f) ? dt : (expm1f(xx) / ar);
        bbar[idx] = __float2bfloat16(ratio * bmat[idx]);
    } else {
        int s = threadIdx.x;
        float la = fminf(fmaxf(lna[s], -8.f), 4.f);
        float ar = -expf(la);
        float lt = fminf(fmaxf(ldt[s], -8.f), 1.f);
        float dt = expf(lt);
        float ab = expf(dt * ar);
        abar[s] = ab;
        float p = ab;
#pragma unroll
        for (int j = 0; j < 5; ++j) p *= p;     // a^32 by squaring
        aw32[s] = p;
    }
}

// ---------------- K2: GEMM + e32 -> ub[b][t][s] (bf16) ---------------------
// Block (c,b): 32t x 256s tile. e32 Horner straight from bf16-rounded acc;
// LDS-transposed epilogue emits ONE contiguous 16 KiB run.
// 2048 blocks, ~6 blocks/CU (16 KiB LDS, low VGPR).
__global__ __launch_bounds__(256, 6) void k_gemm(
        const float* __restrict__ x, const __hip_bfloat16* __restrict__ bbar,
        const float* __restrict__ abar,
        __hip_bfloat16* __restrict__ ub, float* __restrict__ e32) {
    const int c = blockIdx.x, b = blockIdx.y;
    __shared__ char LDS[WND * 512];    // 16 KiB: A-stage in [0,8K), then P
    const int tid = threadIdx.x, lane = tid & 63, w = tid >> 6;
    const int l15 = lane & 15, l4 = lane >> 4;

    // Stage A: rows t'=0..31 of batch b, fp32 -> bf16, swizzle ^((row&7)<<4)
#pragma unroll
    for (int k = 0; k < 4; ++k) {
        int idx = tid + k * 256;
        int row = idx >> 5, seg = idx & 31;
        float4 v = *(const float4*)(x + ((size_t)(c * WND + row) * B_ + b) * D_ + seg * 4);
        __hip_bfloat162 lo = __float22bfloat162_rn(make_float2(v.x, v.y));
        __hip_bfloat162 hi = __float22bfloat162_rn(make_float2(v.z, v.w));
        uint2 pk = { *(unsigned*)&lo, *(unsigned*)&hi };
        int off = (row * 256 + seg * 8) ^ ((row & 7) << 4);
        *(uint2*)(LDS + off) = pk;
    }
    __syncthreads();

    // MFMA: wave w owns s in [w*64,(w+1)*64); acc row = i*16 + l4*4 + r
    f32x4 acc[2][4] = {};
    for (int j = 0; j < 4; ++j) {
        bf8 bfrag[4];
        int s = w * 64 + j * 16 + l15;
#pragma unroll
        for (int kk = 0; kk < 4; ++kk)
            bfrag[kk] = *(const bf8*)((const short*)bbar + s * D_ + kk * 32 + l4 * 8);
#pragma unroll
        for (int i = 0; i < 2; ++i) {
            bf8 af[4];
            int tr = i * 16 + l15;
#pragma unroll
            for (int kk = 0; kk < 4; ++kk) {
                int off = (tr * 256 + kk * 64 + l4 * 16) ^ ((tr & 7) << 4);
                af[kk] = *(const bf8*)(LDS + off);
            }
#pragma unroll
            for (int kk = 0; kk < 4; ++kk)
                acc[i][j] = __builtin_amdgcn_mfma_f32_16x16x32_bf16(
                                af[kk], bfrag[kk], acc[i][j], 0, 0, 0);
        }
    }
    __syncthreads();   // all A reads done; LDS becomes P[t'][s] bf16

    // e32 Horner (bf16-rounded, matches scan input) + P -> LDS (swizzled).
    // t' = i*16 + l4*4 + r ; weight a^(31-t') = a^(3-r)*a^(16(1-i))*a^(4(3-l4))
#pragma unroll
    for (int j = 0; j < 4; ++j) {
        int s = w * 64 + j * 16 + l15;
        float a  = abar[s];
        float a2 = a * a, a4 = a2 * a2, a8 = a4 * a4, a16 = a8 * a8;
        float lf = (l4 == 0) ? a8 * a4 : (l4 == 1) ? a8 : (l4 == 2) ? a4 : 1.f;
        float e = 0.f;
#pragma unroll
        for (int i = 0; i < 2; ++i) {
            unsigned short h0 = bf16bits(acc[i][j][0]);
            unsigned short h1 = bf16bits(acc[i][j][1]);
            unsigned short h2 = bf16bits(acc[i][j][2]);
            unsigned short h3 = bf16bits(acc[i][j][3]);
            float inner = bfbits(h0);
            inner = fmaf(inner, a, bfbits(h1));
            inner = fmaf(inner, a, bfbits(h2));
            inner = fmaf(inner, a, bfbits(h3));
            e = fmaf(e, a16, inner);
            int row0 = i * 16 + l4 * 4;            // ((row>>2)&3) == l4 here
            *(unsigned short*)(LDS + (((row0    ) * 512 + s * 2) ^ (l4 << 5))) = h0;
            *(unsigned short*)(LDS + (((row0 + 1) * 512 + s * 2) ^ (l4 << 5))) = h1;
            *(unsigned short*)(LDS + (((row0 + 2) * 512 + s * 2) ^ (l4 << 5))) = h2;
            *(unsigned short*)(LDS + (((row0 + 3) * 512 + s * 2) ^ (l4 << 5))) = h3;
        }
        e *= lf;
        e += __shfl_xor(e, 16);
        e += __shfl_xor(e, 32);
        if (l4 == 0) e32[((size_t)c * B_ + b) * S_ + s] = e;
    }
    __syncthreads();

    // Flat copy: ONE contiguous 16 KiB run -> ub[b][c*32 .. c*32+31][*]
    char* op = (char*)(ub + ((size_t)b * T_ + c * WND) * S_);
#pragma unroll
    for (int k = 0; k < 4; ++k) {
        int o = k * 4096 + tid * 16;
        int swz = (2 * k + (w >> 1)) & 3;          // = ((o>>11)&3)
        uint4 v = *(uint4*)(LDS + (o ^ (swz << 5)));
        *(uint4*)(op + o) = v;
    }
}

// ---------------- K3: fused carry + per-chunk scan + out, x2 s-vectorized --
// Block (c,g): wave w -> b = g*2 + (w>>1), s-half = (w&1); lane -> 2 s values.
// Carry-in via fixed-trip predicated Horner over e32 partials (L2-hot).
__global__ __launch_bounds__(256) void k_scan(
        const __hip_bfloat16* __restrict__ ub, const float* __restrict__ e32,
        const float* __restrict__ abar, const float* __restrict__ aw32,
        const float* __restrict__ z0, float* __restrict__ out) {
    const int c = blockIdx.x, g = blockIdx.y;
    const int w = threadIdx.x >> 6, lane = threadIdx.x & 63;
    const int b = g * 2 + (w >> 1);
    const int s0 = (w & 1) * 128 + lane * 2;

    float2 a  = *(const float2*)(abar + s0);
    float2 aw = *(const float2*)(aw32 + s0);
    float2 z  = *(const float2*)(z0 + b * S_ + s0);

    // carry: 128 fixed trips, batch-16 independent loads then predicated fma
#pragma unroll
    for (int cp0 = 0; cp0 < C4; cp0 += 16) {
        float2 ev[16];
#pragma unroll
        for (int k = 0; k < 16; ++k)
            ev[k] = *(const float2*)(e32 + ((size_t)(cp0 + k) * B_ + b) * S_ + s0);
#pragma unroll
        for (int k = 0; k < 16; ++k) {
            float zx = fmaf(aw.x, z.x, ev[k].x);
            float zy = fmaf(aw.y, z.y, ev[k].y);
            bool p = (cp0 + k) < c;
            z.x = p ? zx : z.x;
            z.y = p ? zy : z.y;
        }
    }

    // scan own chunk, coalesced
    const char* up = (const char*)(ub + ((size_t)b * T_ + c * WND) * S_ + s0);
    float* op = out + ((size_t)(c * WND) * B_ + b) * S_ + s0;
#pragma unroll 8
    for (int t = 0; t < WND; ++t) {
        ushort2 v = *(const ushort2*)up;           // 4 B/lane, 256 B/wave
        z.x = fmaf(a.x, z.x, bfbits(v.x));
        z.y = fmaf(a.y, z.y, bfbits(v.y));
        *(float2*)op = z;                          // 8 B/lane, 512 B/wave
        up += S_ * 2;
        op += (size_t)B_ * S_;
    }
}

extern "C" void kernel_launch(void* const* d_in, const int* in_sizes, int n_in,
                              void* d_out, int out_size, void* d_ws, size_t ws_size,
                              hipStream_t stream) {
    const float* x   = (const float*)d_in[0];  // [T,B,D]
    const float* z0  = (const float*)d_in[1];  // [B,S]
    const float* lna = (const float*)d_in[2];  // [S]
    const float* bm  = (const float*)d_in[3];  // [S,D]
    const float* ldt = (const float*)d_in[4];  // [S]
    float* out = (float*)d_out;

    char* ws = (char*)d_ws;
    float*          abar = (float*)ws;                        // 1 KiB
    float*          aw32 = (float*)(ws + 4096);               // 1 KiB
    __hip_bfloat16* bbar = (__hip_bfloat16*)(ws + 8192);      // 64 KiB
    float*          e32  = (float*)(ws + (128 << 10));        // 2 MiB [c][b][s]
    __hip_bfloat16* ub   = (__hip_bfloat16*)(ws + (4 << 20)); // 32 MiB [b][t][s]

    k_params<<<129, 256, 0, stream>>>(lna, bm, ldt, abar, aw32, bbar);
    k_gemm<<<dim3(C4, B_), 256, 0, stream>>>(x, bbar, abar, ub, e32);
    k_scan<<<dim3(C4, B_/2), 256, 0, stream>>>(ub, e32, abar, aw32, z0, out);
}

// Round 12
// 60.383 us; speedup vs baseline: 1.1458x; 1.1458x over previous
//
#include <hip/hip_runtime.h>
#include <hip/hip_bf16.h>

// Problem constants (S4Layer: T=4096, B=16, D=128, S=256)
#define T_  4096
#define B_  16
#define D_  128
#define S_  256
#define WND 64             // chunk length = GEMM t-tile
#define C4  (T_/WND)       // 64 chunks
#define SH  128            // s per gemm block (half)

using bf8   = __attribute__((ext_vector_type(8))) short;   // 8 bf16 (4 VGPRs)
using f32x4 = __attribute__((ext_vector_type(4))) float;   // MFMA acc

__device__ inline float bfbits(unsigned short h) {
    return __builtin_bit_cast(float, (unsigned)h << 16);
}
__device__ inline unsigned short bf16bits(float f) {
    return __hip_bfloat16_raw(__float2bfloat16(f)).x;
}

// ---------------- K1: parameters (hoisted, computed ONCE) -------------------
__global__ __launch_bounds__(256) void k_params(
        const float* __restrict__ lna, const float* __restrict__ bmat,
        const float* __restrict__ ldt,
        float* __restrict__ abar, float* __restrict__ a64,
        __hip_bfloat16* __restrict__ bbar) {
    if (blockIdx.x < 128) {
        int idx = blockIdx.x * 256 + threadIdx.x;   // (s,d)
        int s = idx >> 7;
        float la = fminf(fmaxf(lna[s], -8.f), 4.f);
        float ar = -expf(la);
        float lt = fminf(fmaxf(ldt[s], -8.f), 1.f);
        float dt = expf(lt);
        float xx = dt * ar;
        float ratio = (fabsf(xx) < 1e-6f) ? dt : (expm1f(xx) / ar);
        bbar[idx] = __float2bfloat16(ratio * bmat[idx]);
    } else {
        int s = threadIdx.x;
        float la = fminf(fmaxf(lna[s], -8.f), 4.f);
        float ar = -expf(la);
        float lt = fminf(fmaxf(ldt[s], -8.f), 1.f);
        float dt = expf(lt);
        float ab = expf(dt * ar);
        abar[s] = ab;
        float p = ab;
#pragma unroll
        for (int j = 0; j < 6; ++j) p *= p;     // a^64 by squaring
        a64[s] = p;
    }
}

// ---------------- K2: GEMM + e64 -> ub2[h][b][t][s128] (bf16) --------------
// Block (c,b,h): 64t x 128s tile (s-split halves per-block serial work).
// Adjacent blockIdx.x pairs share the A-tile (h twin) -> L2 hit on stage.
// A-stage and P share ONE 16 KiB LDS buffer; output is one contiguous
// 16 KiB run. e64 Horner from bf16-rounded acc (identical arithmetic).
__global__ __launch_bounds__(256, 6) void k_gemm(
        const float* __restrict__ x, const __hip_bfloat16* __restrict__ bbar,
        const float* __restrict__ abar,
        __hip_bfloat16* __restrict__ ub2, float* __restrict__ e64) {
    const int c = blockIdx.x >> 1, h = blockIdx.x & 1, b = blockIdx.y;
    __shared__ char LDS[WND * 256];    // 16 KiB: A-stage [64][128]bf16, then P [64][128]bf16
    const int tid = threadIdx.x, lane = tid & 63, w = tid >> 6;
    const int l15 = lane & 15, l4 = lane >> 4;

    // Stage A: rows t'=0..63 of batch b, fp32 -> bf16, swizzle ^((row&7)<<4)
#pragma unroll
    for (int k = 0; k < 8; ++k) {
        int idx = tid + k * 256;
        int row = idx >> 5, seg = idx & 31;
        float4 v = *(const float4*)(x + ((size_t)(c * WND + row) * B_ + b) * D_ + seg * 4);
        __hip_bfloat162 lo = __float22bfloat162_rn(make_float2(v.x, v.y));
        __hip_bfloat162 hi = __float22bfloat162_rn(make_float2(v.z, v.w));
        uint2 pk = { *(unsigned*)&lo, *(unsigned*)&hi };
        int off = (row * 256 + seg * 8) ^ ((row & 7) << 4);
        *(uint2*)(LDS + off) = pk;
    }
    __syncthreads();

    // MFMA: wave w owns s_local in [w*32,(w+1)*32); acc row = i*16 + l4*4 + r
    f32x4 acc[4][2] = {};
    for (int j = 0; j < 2; ++j) {
        bf8 bfrag[4];
        int sg = h * SH + w * 32 + j * 16 + l15;       // global s
#pragma unroll
        for (int kk = 0; kk < 4; ++kk)
            bfrag[kk] = *(const bf8*)((const short*)bbar + sg * D_ + kk * 32 + l4 * 8);
#pragma unroll
        for (int i = 0; i < 4; ++i) {
            bf8 af[4];
            int tr = i * 16 + l15;
#pragma unroll
            for (int kk = 0; kk < 4; ++kk) {
                int off = (tr * 256 + kk * 64 + l4 * 16) ^ ((tr & 7) << 4);
                af[kk] = *(const bf8*)(LDS + off);
            }
#pragma unroll
            for (int kk = 0; kk < 4; ++kk)
                acc[i][j] = __builtin_amdgcn_mfma_f32_16x16x32_bf16(
                                af[kk], bfrag[kk], acc[i][j], 0, 0, 0);
        }
    }
    __syncthreads();   // all A reads done; LDS becomes P[t'][s_local] bf16

    // e64 Horner (bf16-rounded, matches scan input) + P -> LDS (swizzled).
    // t' = i*16 + l4*4 + r ; weight a^(63-t') = a^(3-r)*a^(16(3-i))*a^(4(3-l4))
#pragma unroll
    for (int j = 0; j < 2; ++j) {
        int sl = w * 32 + j * 16 + l15;                // local s in [0,128)
        int sg = h * SH + sl;
        float a  = abar[sg];
        float a2 = a * a, a4 = a2 * a2, a8 = a4 * a4, a16 = a8 * a8;
        float lf = (l4 == 0) ? a8 * a4 : (l4 == 1) ? a8 : (l4 == 2) ? a4 : 1.f;
        float e = 0.f;
#pragma unroll
        for (int i = 0; i < 4; ++i) {
            unsigned short h0 = bf16bits(acc[i][j][0]);
            unsigned short h1 = bf16bits(acc[i][j][1]);
            unsigned short h2 = bf16bits(acc[i][j][2]);
            unsigned short h3 = bf16bits(acc[i][j][3]);
            float inner = bfbits(h0);
            inner = fmaf(inner, a, bfbits(h1));
            inner = fmaf(inner, a, bfbits(h2));
            inner = fmaf(inner, a, bfbits(h3));
            e = fmaf(e, a16, inner);
            int row0 = i * 16 + l4 * 4;                // ((row>>2)&3) == l4 here
            *(unsigned short*)(LDS + (((row0    ) * 256 + sl * 2) ^ (l4 << 5))) = h0;
            *(unsigned short*)(LDS + (((row0 + 1) * 256 + sl * 2) ^ (l4 << 5))) = h1;
            *(unsigned short*)(LDS + (((row0 + 2) * 256 + sl * 2) ^ (l4 << 5))) = h2;
            *(unsigned short*)(LDS + (((row0 + 3) * 256 + sl * 2) ^ (l4 << 5))) = h3;
        }
        e *= lf;
        e += __shfl_xor(e, 16);
        e += __shfl_xor(e, 32);
        if (l4 == 0) e64[((size_t)c * B_ + b) * S_ + sg] = e;
    }
    __syncthreads();

    // Flat copy: ONE contiguous 16 KiB run -> ub2[h][b][c*64 .. +63][0..128)
    char* op = (char*)(ub2 + (((size_t)h * B_ + b) * T_ + c * WND) * SH);
#pragma unroll
    for (int k = 0; k < 4; ++k) {
        int o = k * 4096 + tid * 16;
        uint4 v = *(uint4*)(LDS + (o ^ (((o >> 10) & 3) << 5)));
        *(uint4*)(op + o) = v;
    }
}

// ---------------- K3: fused carry + per-chunk scan + out, x2 s-vectorized --
// Block (c,g): wave w -> b = g*2 + (w>>1), h = w&1; lane -> 2 s values.
// Carry-in via fixed-trip predicated Horner over e64 partials (L2-hot).
__global__ __launch_bounds__(256) void k_scan(
        const __hip_bfloat16* __restrict__ ub2, const float* __restrict__ e64,
        const float* __restrict__ abar, const float* __restrict__ a64,
        const float* __restrict__ z0, float* __restrict__ out) {
    const int c = blockIdx.x, g = blockIdx.y;
    const int w = threadIdx.x >> 6, lane = threadIdx.x & 63;
    const int b = g * 2 + (w >> 1);
    const int h = w & 1;
    const int s0 = h * SH + lane * 2;

    float2 a  = *(const float2*)(abar + s0);
    float2 aw = *(const float2*)(a64 + s0);
    float2 z  = *(const float2*)(z0 + b * S_ + s0);

    // carry: 64 fixed trips, batch-16 independent loads then predicated fma
#pragma unroll
    for (int cp0 = 0; cp0 < C4; cp0 += 16) {
        float2 ev[16];
#pragma unroll
        for (int k = 0; k < 16; ++k)
            ev[k] = *(const float2*)(e64 + ((size_t)(cp0 + k) * B_ + b) * S_ + s0);
#pragma unroll
        for (int k = 0; k < 16; ++k) {
            float zx = fmaf(aw.x, z.x, ev[k].x);
            float zy = fmaf(aw.y, z.y, ev[k].y);
            bool p = (cp0 + k) < c;
            z.x = p ? zx : z.x;
            z.y = p ? zy : z.y;
        }
    }

    // scan own chunk from ub2 half-layout, coalesced
    const char* up = (const char*)(ub2 + (((size_t)h * B_ + b) * T_ + c * WND) * SH
                                   + lane * 2);
    float* op = out + ((size_t)(c * WND) * B_ + b) * S_ + s0;
#pragma unroll 8
    for (int t = 0; t < WND; ++t) {
        ushort2 v = *(const ushort2*)up;           // 4 B/lane, 256 B/wave
        z.x = fmaf(a.x, z.x, bfbits(v.x));
        z.y = fmaf(a.y, z.y, bfbits(v.y));
        *(float2*)op = z;                          // 8 B/lane, 512 B/wave
        up += SH * 2;
        op += (size_t)B_ * S_;
    }
}

extern "C" void kernel_launch(void* const* d_in, const int* in_sizes, int n_in,
                              void* d_out, int out_size, void* d_ws, size_t ws_size,
                              hipStream_t stream) {
    const float* x   = (const float*)d_in[0];  // [T,B,D]
    const float* z0  = (const float*)d_in[1];  // [B,S]
    const float* lna = (const float*)d_in[2];  // [S]
    const float* bm  = (const float*)d_in[3];  // [S,D]
    const float* ldt = (const float*)d_in[4];  // [S]
    float* out = (float*)d_out;

    char* ws = (char*)d_ws;
    float*          abar = (float*)ws;                        // 1 KiB
    float*          a64  = (float*)(ws + 4096);               // 1 KiB
    __hip_bfloat16* bbar = (__hip_bfloat16*)(ws + 8192);      // 64 KiB
    float*          e64  = (float*)(ws + (128 << 10));        // 1 MiB [c][b][s]
    __hip_bfloat16* ub2  = (__hip_bfloat16*)(ws + (4 << 20)); // 32 MiB [h][b][t][s128]

    k_params<<<129, 256, 0, stream>>>(lna, bm, ldt, abar, a64, bbar);
    k_gemm<<<dim3(C4 * 2, B_), 256, 0, stream>>>(x, bbar, abar, ub2, e64);
    k_scan<<<dim3(C4, B_ / 2), 256, 0, stream>>>(ub2, e64, abar, a64, z0, out);
}

// Round 13
// 52.647 us; speedup vs baseline: 1.3142x; 1.1469x over previous
//
#include <hip/hip_runtime.h>
#include <hip/hip_bf16.h>

// Problem constants (S4Layer: T=4096, B=16, D=128, S=256)
#define T_  4096
#define B_  16
#define D_  128
#define S_  256
#define WND 64             // chunk length = GEMM t-tile
#define C4  (T_/WND)       // 64 chunks

using bf8   = __attribute__((ext_vector_type(8))) short;   // 8 bf16 (4 VGPRs)
using f32x4 = __attribute__((ext_vector_type(4))) float;   // MFMA acc

__device__ inline float bfbits(unsigned short h) {
    return __builtin_bit_cast(float, (unsigned)h << 16);
}
__device__ inline unsigned short bf16bits(float f) {
    return __hip_bfloat16_raw(__float2bfloat16(f)).x;
}

// ---------------- K1: parameters (hoisted, computed ONCE) -------------------
__global__ __launch_bounds__(256) void k_params(
        const float* __restrict__ lna, const float* __restrict__ bmat,
        const float* __restrict__ ldt,
        float* __restrict__ abar, float* __restrict__ a64,
        __hip_bfloat16* __restrict__ bbar) {
    if (blockIdx.x < 128) {
        int idx = blockIdx.x * 256 + threadIdx.x;   // (s,d)
        int s = idx >> 7;
        float la = fminf(fmaxf(lna[s], -8.f), 4.f);
        float ar = -expf(la);
        float lt = fminf(fmaxf(ldt[s], -8.f), 1.f);
        float dt = expf(lt);
        float xx = dt * ar;
        float ratio = (fabsf(xx) < 1e-6f) ? dt : (expm1f(xx) / ar);
        bbar[idx] = __float2bfloat16(ratio * bmat[idx]);
    } else {
        int s = threadIdx.x;
        float la = fminf(fmaxf(lna[s], -8.f), 4.f);
        float ar = -expf(la);
        float lt = fminf(fmaxf(ldt[s], -8.f), 1.f);
        float dt = expf(lt);
        float ab = expf(dt * ar);
        abar[s] = ab;
        float p = ab;
#pragma unroll
        for (int j = 0; j < 6; ++j) p *= p;     // a^64 by squaring
        a64[s] = p;
    }
}

// ---------------- K2: GEMM + e64 -> ub[b][t][s] (bf16) ---------------------
// Block (c,b): 64t x 256s tile (R8 structure, verbatim). e64 Horner straight
// from bf16-rounded acc; LDS-transposed epilogue emits ONE contiguous 32 KiB
// run. 1024 blocks; 5 blocks/CU (32 KiB LDS x 5 = 160 KiB exactly).
__global__ __launch_bounds__(256, 5) void k_gemm(
        const float* __restrict__ x, const __hip_bfloat16* __restrict__ bbar,
        const float* __restrict__ abar,
        __hip_bfloat16* __restrict__ ub, float* __restrict__ e64) {
    const int c = blockIdx.x, b = blockIdx.y;
    __shared__ char LDS[WND * 512];    // 32 KiB: A-stage in [0,16K), then P
    const int tid = threadIdx.x, lane = tid & 63, w = tid >> 6;
    const int l15 = lane & 15, l4 = lane >> 4;

    // Stage A: rows t'=0..63 of batch b, fp32 -> bf16, swizzle ^((row&7)<<4)
#pragma unroll
    for (int k = 0; k < 8; ++k) {
        int idx = tid + k * 256;
        int row = idx >> 5, seg = idx & 31;
        float4 v = *(const float4*)(x + ((size_t)(c * WND + row) * B_ + b) * D_ + seg * 4);
        __hip_bfloat162 lo = __float22bfloat162_rn(make_float2(v.x, v.y));
        __hip_bfloat162 hi = __float22bfloat162_rn(make_float2(v.z, v.w));
        uint2 pk = { *(unsigned*)&lo, *(unsigned*)&hi };
        int off = (row * 256 + seg * 8) ^ ((row & 7) << 4);
        *(uint2*)(LDS + off) = pk;
    }
    __syncthreads();

    // MFMA: wave w owns s in [w*64,(w+1)*64); acc row = i*16 + l4*4 + r
    f32x4 acc[4][4] = {};
    for (int j = 0; j < 4; ++j) {
        bf8 bfrag[4];
        int s = w * 64 + j * 16 + l15;
#pragma unroll
        for (int kk = 0; kk < 4; ++kk)
            bfrag[kk] = *(const bf8*)((const short*)bbar + s * D_ + kk * 32 + l4 * 8);
#pragma unroll
        for (int i = 0; i < 4; ++i) {
            bf8 af[4];
            int tr = i * 16 + l15;
#pragma unroll
            for (int kk = 0; kk < 4; ++kk) {
                int off = (tr * 256 + kk * 64 + l4 * 16) ^ ((tr & 7) << 4);
                af[kk] = *(const bf8*)(LDS + off);
            }
#pragma unroll
            for (int kk = 0; kk < 4; ++kk)
                acc[i][j] = __builtin_amdgcn_mfma_f32_16x16x32_bf16(
                                af[kk], bfrag[kk], acc[i][j], 0, 0, 0);
        }
    }
    __syncthreads();   // all A reads done; LDS becomes P[t'][s] bf16

    // e64 Horner (bf16-rounded, matches scan input) + P -> LDS (swizzled).
    // t' = i*16 + l4*4 + r ; weight a^(63-t') = a^(3-r)*a^(16(3-i))*a^(4(3-l4))
#pragma unroll
    for (int j = 0; j < 4; ++j) {
        int s = w * 64 + j * 16 + l15;
        float a  = abar[s];
        float a2 = a * a, a4 = a2 * a2, a8 = a4 * a4, a16 = a8 * a8;
        float lf = (l4 == 0) ? a8 * a4 : (l4 == 1) ? a8 : (l4 == 2) ? a4 : 1.f;
        float e = 0.f;
#pragma unroll
        for (int i = 0; i < 4; ++i) {
            unsigned short h0 = bf16bits(acc[i][j][0]);
            unsigned short h1 = bf16bits(acc[i][j][1]);
            unsigned short h2 = bf16bits(acc[i][j][2]);
            unsigned short h3 = bf16bits(acc[i][j][3]);
            float inner = bfbits(h0);
            inner = fmaf(inner, a, bfbits(h1));
            inner = fmaf(inner, a, bfbits(h2));
            inner = fmaf(inner, a, bfbits(h3));
            e = fmaf(e, a16, inner);
            int row0 = i * 16 + l4 * 4;            // ((row>>2)&3) == l4 here
            *(unsigned short*)(LDS + (((row0    ) * 512 + s * 2) ^ (l4 << 5))) = h0;
            *(unsigned short*)(LDS + (((row0 + 1) * 512 + s * 2) ^ (l4 << 5))) = h1;
            *(unsigned short*)(LDS + (((row0 + 2) * 512 + s * 2) ^ (l4 << 5))) = h2;
            *(unsigned short*)(LDS + (((row0 + 3) * 512 + s * 2) ^ (l4 << 5))) = h3;
        }
        e *= lf;
        e += __shfl_xor(e, 16);
        e += __shfl_xor(e, 32);
        if (l4 == 0) e64[((size_t)c * B_ + b) * S_ + s] = e;
    }
    __syncthreads();

    // Flat copy: ONE contiguous 32 KiB run -> ub[b][c*64 .. c*64+63][*]
    char* op = (char*)(ub + ((size_t)b * T_ + c * WND) * S_);
#pragma unroll
    for (int k = 0; k < 8; ++k) {
        int o = k * 4096 + tid * 16;
        int swz = (2 * k + (w >> 1)) & 3;          // = ((o>>11)&3)
        uint4 v = *(uint4*)(LDS + (o ^ (swz << 5)));
        *(uint4*)(op + o) = v;
    }
}

// ---------------- K3: fused carry + per-chunk scan + out, x2 s-vectorized --
// Block (c,g): wave w -> b = g*2 + (w>>1), s-half = (w&1); lane -> 2 s values.
// Carry-in via fixed-trip predicated Horner over e64 partials (L2-hot;
// this exact pattern validated R9-R12).
__global__ __launch_bounds__(256) void k_scan(
        const __hip_bfloat16* __restrict__ ub, const float* __restrict__ e64,
        const float* __restrict__ abar, const float* __restrict__ a64,
        const float* __restrict__ z0, float* __restrict__ out) {
    const int c = blockIdx.x, g = blockIdx.y;
    const int w = threadIdx.x >> 6, lane = threadIdx.x & 63;
    const int b = g * 2 + (w >> 1);
    const int s0 = (w & 1) * 128 + lane * 2;

    float2 a  = *(const float2*)(abar + s0);
    float2 aw = *(const float2*)(a64 + s0);
    float2 z  = *(const float2*)(z0 + b * S_ + s0);

    // carry: 64 fixed trips, batch-16 independent loads then predicated fma
#pragma unroll
    for (int cp0 = 0; cp0 < C4; cp0 += 16) {
        float2 ev[16];
#pragma unroll
        for (int k = 0; k < 16; ++k)
            ev[k] = *(const float2*)(e64 + ((size_t)(cp0 + k) * B_ + b) * S_ + s0);
#pragma unroll
        for (int k = 0; k < 16; ++k) {
            float zx = fmaf(aw.x, z.x, ev[k].x);
            float zy = fmaf(aw.y, z.y, ev[k].y);
            bool p = (cp0 + k) < c;
            z.x = p ? zx : z.x;
            z.y = p ? zy : z.y;
        }
    }

    // scan own chunk, coalesced
    const char* up = (const char*)(ub + ((size_t)b * T_ + c * WND) * S_ + s0);
    float* op = out + ((size_t)(c * WND) * B_ + b) * S_ + s0;
#pragma unroll 8
    for (int t = 0; t < WND; ++t) {
        ushort2 v = *(const ushort2*)up;           // 4 B/lane, 256 B/wave
        z.x = fmaf(a.x, z.x, bfbits(v.x));
        z.y = fmaf(a.y, z.y, bfbits(v.y));
        *(float2*)op = z;                          // 8 B/lane, 512 B/wave
        up += S_ * 2;
        op += (size_t)B_ * S_;
    }
}

extern "C" void kernel_launch(void* const* d_in, const int* in_sizes, int n_in,
                              void* d_out, int out_size, void* d_ws, size_t ws_size,
                              hipStream_t stream) {
    const float* x   = (const float*)d_in[0];  // [T,B,D]
    const float* z0  = (const float*)d_in[1];  // [B,S]
    const float* lna = (const float*)d_in[2];  // [S]
    const float* bm  = (const float*)d_in[3];  // [S,D]
    const float* ldt = (const float*)d_in[4];  // [S]
    float* out = (float*)d_out;

    char* ws = (char*)d_ws;
    float*          abar = (float*)ws;                        // 1 KiB
    float*          a64  = (float*)(ws + 4096);               // 1 KiB
    __hip_bfloat16* bbar = (__hip_bfloat16*)(ws + 8192);      // 64 KiB
    float*          e64  = (float*)(ws + (128 << 10));        // 1 MiB [c][b][s]
    __hip_bfloat16* ub   = (__hip_bfloat16*)(ws + (4 << 20)); // 32 MiB [b][t][s]

    k_params<<<129, 256, 0, stream>>>(lna, bm, ldt, abar, a64, bbar);
    k_gemm<<<dim3(C4, B_), 256, 0, stream>>>(x, bbar, abar, ub, e64);
    k_scan<<<dim3(C4, B_ / 2), 256, 0, stream>>>(ub, e64, abar, a64, z0, out);
}

// Round 14
// 48.777 us; speedup vs baseline: 1.4185x; 1.0793x over previous
//
#include <hip/hip_runtime.h>
#include <hip/hip_bf16.h>

// Problem constants (S4Layer: T=4096, B=16, D=128, S=256)
#define T_  4096
#define B_  16
#define D_  128
#define S_  256
#define WND 64             // chunk length = GEMM t-tile
#define C4  (T_/WND)       // 64 chunks

using bf8   = __attribute__((ext_vector_type(8))) short;   // 8 bf16 (4 VGPRs)
using f32x4 = __attribute__((ext_vector_type(4))) float;   // MFMA acc

__device__ inline float bfbits(unsigned short h) {
    return __builtin_bit_cast(float, (unsigned)h << 16);
}
__device__ inline unsigned short bf16bits(float f) {
    return __hip_bfloat16_raw(__float2bfloat16(f)).x;
}

// ---------------- K1: parameters (hoisted, computed ONCE) -------------------
__global__ __launch_bounds__(256) void k_params(
        const float* __restrict__ lna, const float* __restrict__ bmat,
        const float* __restrict__ ldt,
        float* __restrict__ abar, float* __restrict__ a64,
        __hip_bfloat16* __restrict__ bbar) {
    if (blockIdx.x < 128) {
        int idx = blockIdx.x * 256 + threadIdx.x;   // (s,d)
        int s = idx >> 7;
        float la = fminf(fmaxf(lna[s], -8.f), 4.f);
        float ar = -expf(la);
        float lt = fminf(fmaxf(ldt[s], -8.f), 1.f);
        float dt = expf(lt);
        float xx = dt * ar;
        float ratio = (fabsf(xx) < 1e-6f) ? dt : (expm1f(xx) / ar);
        bbar[idx] = __float2bfloat16(ratio * bmat[idx]);
    } else {
        int s = threadIdx.x;
        float la = fminf(fmaxf(lna[s], -8.f), 4.f);
        float ar = -expf(la);
        float lt = fminf(fmaxf(ldt[s], -8.f), 1.f);
        float dt = expf(lt);
        float ab = expf(dt * ar);
        abar[s] = ab;
        float p = ab;
#pragma unroll
        for (int j = 0; j < 6; ++j) p *= p;     // a^64 by squaring
        a64[s] = p;
    }
}

// ---------------- K2: GEMM + e64 -> ub[b][t][s] (bf16) ---------------------
// Block (c,b): 64t x 256s tile (R8 structure, verbatim, (256,4)). e64 Horner
// straight from bf16-rounded acc; LDS-transposed epilogue emits ONE
// contiguous 32 KiB run. 1024 blocks, 4 blocks/CU.
__global__ __launch_bounds__(256, 4) void k_gemm(
        const float* __restrict__ x, const __hip_bfloat16* __restrict__ bbar,
        const float* __restrict__ abar,
        __hip_bfloat16* __restrict__ ub, float* __restrict__ e64) {
    const int c = blockIdx.x, b = blockIdx.y;
    __shared__ char LDS[WND * 512];    // 32 KiB: A-stage in [0,16K), then P
    const int tid = threadIdx.x, lane = tid & 63, w = tid >> 6;
    const int l15 = lane & 15, l4 = lane >> 4;

    // Stage A: rows t'=0..63 of batch b, fp32 -> bf16, swizzle ^((row&7)<<4)
#pragma unroll
    for (int k = 0; k < 8; ++k) {
        int idx = tid + k * 256;
        int row = idx >> 5, seg = idx & 31;
        float4 v = *(const float4*)(x + ((size_t)(c * WND + row) * B_ + b) * D_ + seg * 4);
        __hip_bfloat162 lo = __float22bfloat162_rn(make_float2(v.x, v.y));
        __hip_bfloat162 hi = __float22bfloat162_rn(make_float2(v.z, v.w));
        uint2 pk = { *(unsigned*)&lo, *(unsigned*)&hi };
        int off = (row * 256 + seg * 8) ^ ((row & 7) << 4);
        *(uint2*)(LDS + off) = pk;
    }
    __syncthreads();

    // MFMA: wave w owns s in [w*64,(w+1)*64); acc row = i*16 + l4*4 + r
    f32x4 acc[4][4] = {};
    for (int j = 0; j < 4; ++j) {
        bf8 bfrag[4];
        int s = w * 64 + j * 16 + l15;
#pragma unroll
        for (int kk = 0; kk < 4; ++kk)
            bfrag[kk] = *(const bf8*)((const short*)bbar + s * D_ + kk * 32 + l4 * 8);
#pragma unroll
        for (int i = 0; i < 4; ++i) {
            bf8 af[4];
            int tr = i * 16 + l15;
#pragma unroll
            for (int kk = 0; kk < 4; ++kk) {
                int off = (tr * 256 + kk * 64 + l4 * 16) ^ ((tr & 7) << 4);
                af[kk] = *(const bf8*)(LDS + off);
            }
#pragma unroll
            for (int kk = 0; kk < 4; ++kk)
                acc[i][j] = __builtin_amdgcn_mfma_f32_16x16x32_bf16(
                                af[kk], bfrag[kk], acc[i][j], 0, 0, 0);
        }
    }
    __syncthreads();   // all A reads done; LDS becomes P[t'][s] bf16

    // e64 Horner (bf16-rounded, matches scan input) + P -> LDS (swizzled).
    // t' = i*16 + l4*4 + r ; weight a^(63-t') = a^(3-r)*a^(16(3-i))*a^(4(3-l4))
#pragma unroll
    for (int j = 0; j < 4; ++j) {
        int s = w * 64 + j * 16 + l15;
        float a  = abar[s];
        float a2 = a * a, a4 = a2 * a2, a8 = a4 * a4, a16 = a8 * a8;
        float lf = (l4 == 0) ? a8 * a4 : (l4 == 1) ? a8 : (l4 == 2) ? a4 : 1.f;
        float e = 0.f;
#pragma unroll
        for (int i = 0; i < 4; ++i) {
            unsigned short h0 = bf16bits(acc[i][j][0]);
            unsigned short h1 = bf16bits(acc[i][j][1]);
            unsigned short h2 = bf16bits(acc[i][j][2]);
            unsigned short h3 = bf16bits(acc[i][j][3]);
            float inner = bfbits(h0);
            inner = fmaf(inner, a, bfbits(h1));
            inner = fmaf(inner, a, bfbits(h2));
            inner = fmaf(inner, a, bfbits(h3));
            e = fmaf(e, a16, inner);
            int row0 = i * 16 + l4 * 4;            // ((row>>2)&3) == l4 here
            *(unsigned short*)(LDS + (((row0    ) * 512 + s * 2) ^ (l4 << 5))) = h0;
            *(unsigned short*)(LDS + (((row0 + 1) * 512 + s * 2) ^ (l4 << 5))) = h1;
            *(unsigned short*)(LDS + (((row0 + 2) * 512 + s * 2) ^ (l4 << 5))) = h2;
            *(unsigned short*)(LDS + (((row0 + 3) * 512 + s * 2) ^ (l4 << 5))) = h3;
        }
        e *= lf;
        e += __shfl_xor(e, 16);
        e += __shfl_xor(e, 32);
        if (l4 == 0) e64[((size_t)c * B_ + b) * S_ + s] = e;
    }
    __syncthreads();

    // Flat copy: ONE contiguous 32 KiB run -> ub[b][c*64 .. c*64+63][*]
    char* op = (char*)(ub + ((size_t)b * T_ + c * WND) * S_);
#pragma unroll
    for (int k = 0; k < 8; ++k) {
        int o = k * 4096 + tid * 16;
        int swz = (2 * k + (w >> 1)) & 3;          // = ((o>>11)&3)
        uint4 v = *(uint4*)(LDS + (o ^ (swz << 5)));
        *(uint4*)(op + o) = v;
    }
}

// ---------------- K3: fused carry + per-chunk scan + out, x2 s-vectorized --
// Block (c,g): wave w -> b = g*2 + (w>>1), s-half = (w&1); lane -> 2 s values.
// Carry-in via fixed-trip predicated Horner over e64 partials (L2-hot).
__global__ __launch_bounds__(256) void k_scan(
        const __hip_bfloat16* __restrict__ ub, const float* __restrict__ e64,
        const float* __restrict__ abar, const float* __restrict__ a64,
        const float* __restrict__ z0, float* __restrict__ out) {
    const int c = blockIdx.x, g = blockIdx.y;
    const int w = threadIdx.x >> 6, lane = threadIdx.x & 63;
    const int b = g * 2 + (w >> 1);
    const int s0 = (w & 1) * 128 + lane * 2;

    float2 a  = *(const float2*)(abar + s0);
    float2 aw = *(const float2*)(a64 + s0);
    float2 z  = *(const float2*)(z0 + b * S_ + s0);

    // carry: 64 fixed trips, batch-16 independent loads then predicated fma
#pragma unroll
    for (int cp0 = 0; cp0 < C4; cp0 += 16) {
        float2 ev[16];
#pragma unroll
        for (int k = 0; k < 16; ++k)
            ev[k] = *(const float2*)(e64 + ((size_t)(cp0 + k) * B_ + b) * S_ + s0);
#pragma unroll
        for (int k = 0; k < 16; ++k) {
            float zx = fmaf(aw.x, z.x, ev[k].x);
            float zy = fmaf(aw.y, z.y, ev[k].y);
            bool p = (cp0 + k) < c;
            z.x = p ? zx : z.x;
            z.y = p ? zy : z.y;
        }
    }

    // scan own chunk, coalesced
    const char* up = (const char*)(ub + ((size_t)b * T_ + c * WND) * S_ + s0);
    float* op = out + ((size_t)(c * WND) * B_ + b) * S_ + s0;
#pragma unroll 8
    for (int t = 0; t < WND; ++t) {
        ushort2 v = *(const ushort2*)up;           // 4 B/lane, 256 B/wave
        z.x = fmaf(a.x, z.x, bfbits(v.x));
        z.y = fmaf(a.y, z.y, bfbits(v.y));
        *(float2*)op = z;                          // 8 B/lane, 512 B/wave
        up += S_ * 2;
        op += (size_t)B_ * S_;
    }
}

extern "C" void kernel_launch(void* const* d_in, const int* in_sizes, int n_in,
                              void* d_out, int out_size, void* d_ws, size_t ws_size,
                              hipStream_t stream) {
    const float* x   = (const float*)d_in[0];  // [T,B,D]
    const float* z0  = (const float*)d_in[1];  // [B,S]
    const float* lna = (const float*)d_in[2];  // [S]
    const float* bm  = (const float*)d_in[3];  // [S,D]
    const float* ldt = (const float*)d_in[4];  // [S]
    float* out = (float*)d_out;

    char* ws = (char*)d_ws;
    float*          abar = (float*)ws;                        // 1 KiB
    float*          a64  = (float*)(ws + 4096);               // 1 KiB
    __hip_bfloat16* bbar = (__hip_bfloat16*)(ws + 8192);      // 64 KiB
    float*          e64  = (float*)(ws + (128 << 10));        // 1 MiB [c][b][s]
    __hip_bfloat16* ub   = (__hip_bfloat16*)(ws + (4 << 20)); // 32 MiB [b][t][s]

    k_params<<<129, 256, 0, stream>>>(lna, bm, ldt, abar, a64, bbar);
    k_gemm<<<dim3(C4, B_), 256, 0, stream>>>(x, bbar, abar, ub, e64);
    k_scan<<<dim3(C4, B_ / 2), 256, 0, stream>>>(ub, e64, abar, a64, z0, out);
}